// Round 2
// baseline (12.773 us; speedup 1.0000x reference)
//
#include <hip/hip_runtime.h>
#include <cfloat>

#define RWIN 5
#define TMAX 8192

// One block per row. 5 waves/block; wave r reduces window r = [floor(rL/5), ceil((r+1)L/5)).
// Windows are each non-empty (L >= 5) and overlap by at most 1 element, so total
// traffic ~ L floats/row. Then a 10-element rank sort (threads 0..9) writes the
// sorted [5 maxes + 5 mins] per row.
__global__ __launch_bounds__(5 * 64) void minmax_sort_kernel(
    const float* __restrict__ in, const int* __restrict__ lengths,
    float* __restrict__ out)
{
    __shared__ float sm[2 * RWIN];

    const int b    = blockIdx.x;
    const int tid  = threadIdx.x;
    const int w    = tid >> 6;   // window index 0..4
    const int lane = tid & 63;

    const int L = lengths[b];
    const float* rowp = in + (size_t)b * TMAX;

    const int s = (w * L) / RWIN;                      // window start (incl)
    const int e = ((w + 1) * L + (RWIN - 1)) / RWIN;   // window end (excl)

    float mx = -__builtin_inff();
    float mn =  __builtin_inff();

    // Aligned float4 body with scalar head/tail.
    int s4 = (s + 3) & ~3; if (s4 > e)  s4 = e;
    int e4 = e & ~3;       if (e4 < s4) e4 = s4;

    for (int t = s + lane; t < s4; t += 64) {          // head (<4 elems)
        const float x = rowp[t];
        mx = fmaxf(mx, x); mn = fminf(mn, x);
    }
    for (int t = s4 + lane * 4; t < e4; t += 64 * 4) { // vector body
        const float4 v = *reinterpret_cast<const float4*>(rowp + t);
        mx = fmaxf(mx, fmaxf(fmaxf(v.x, v.y), fmaxf(v.z, v.w)));
        mn = fminf(mn, fminf(fminf(v.x, v.y), fminf(v.z, v.w)));
    }
    for (int t = e4 + lane; t < e; t += 64) {          // tail (<4 elems)
        const float x = rowp[t];
        mx = fmaxf(mx, x); mn = fminf(mn, x);
    }

    // Wave-level butterfly reduction (64 lanes), max & min together.
    #pragma unroll
    for (int off = 1; off < 64; off <<= 1) {
        mx = fmaxf(mx, __shfl_xor(mx, off));
        mn = fminf(mn, __shfl_xor(mn, off));
    }
    if (lane == 0) { sm[w] = mx; sm[RWIN + w] = mn; }
    __syncthreads();

    // Rank sort of the 10 values (stable via index tie-break); ascending.
    if (tid < 2 * RWIN) {
        const float v = sm[tid];
        int pos = 0;
        #pragma unroll
        for (int j = 0; j < 2 * RWIN; ++j) {
            const float vj = sm[j];
            pos += (int)((vj < v) | ((vj == v) & (j < tid)));
        }
        out[b * (2 * RWIN) + pos] = v;
    }
}

extern "C" void kernel_launch(void* const* d_in, const int* in_sizes, int n_in,
                              void* d_out, int out_size, void* d_ws, size_t ws_size,
                              hipStream_t stream) {
    const float* in      = (const float*)d_in[0];
    const int*   lengths = (const int*)d_in[1];
    float*       out     = (float*)d_out;
    const int B = in_sizes[1];   // 2048 rows
    minmax_sort_kernel<<<B, 5 * 64, 0, stream>>>(in, lengths, out);
}